// Round 6
// baseline (150.916 us; speedup 1.0000x reference)
//
#include <hip/hip_runtime.h>

#define BDIM 128
constexpr int Bn = 16, Cn = 4, Hn = 512, Wn = 512;
constexpr int SL   = Bn * Cn;          // 64 slices
constexpr int WPR  = Wn / 4;           // 128 int4/float4 words per row
constexpr int RPW  = 16;               // rows per wave
constexpr int WAVES = 2;               // waves per block
constexpr int RPB  = WAVES * RPW;      // 32 rows per block
constexpr int CPB  = Hn / RPB;         // 16 chunks per slice
constexpr int NBLK = SL * CPB;         // 1024 blocks = 4/CU, one generation
constexpr float NTOT = 16777216.0f;    // B*C*H*W
constexpr float SMOOTHF = 0.0001f;

__device__ __forceinline__ float wave_reduce(float v) {
#pragma unroll
    for (int off = 32; off > 0; off >>= 1) v += __shfl_down(v, off);
    return v;
}

__device__ __forceinline__ unsigned pack4(int4 c) {
    return (unsigned)c.x | ((unsigned)c.y << 8) |
           ((unsigned)c.z << 16) | ((unsigned)c.w << 24);
}

// Async global->LDS DMA, 16B per lane. Does NOT consume dest VGPRs, so the
// register allocator cannot re-serialize it (rounds 4-5: VGPR-load prologues
// were sunk back to their uses; VALUBusy pinned at 33-36%, 44-50us across
// every structure). vmcnt tracks completion; we wait with counted vmcnt.
__device__ __forceinline__ void gload_lds16(const void* g, void* l) {
    __builtin_amdgcn_global_load_lds(
        (const __attribute__((address_space(1))) void*)g,
        (__attribute__((address_space(3))) void*)l, 16, 0, 0);
}

// Per-wave DMA-ring streaming design (counted-vmcnt, zero barriers).
// Each wave owns a PRIVATE 16 KB LDS region: 4-slot rings of full rows for
// gt (int4) and cmap (float4). Per row iteration:
//   issue [gt(r+4), cmap(r+3)] (4 DMA, clamped rows keep the count fixed)
//   s_waitcnt vmcnt(12)   <- exactly the 3-lookahead batches stay in flight;
//                            the batch for [gt(r+1), cmap(r)] has landed
//   ds_read the rows, compute, roll the 3-row gt window in registers.
// ~1400 cy of lookahead vs ~500-700 cy L3 latency -> waves should not stall.
// No __syncthreads in the loop (wave-private LDS); no device-scope fences
// (round 2: agent-scope per-block fence = L2 flush, 5x regression).
// Lane mapping is contiguous (lane l <-> words l and 64+l) as required by
// the DMA's linear lane*16 dst layout; horizontal neighbors via 6 shfls/row.
__global__ __launch_bounds__(BDIM, 4) void seg_main(const float4* __restrict__ cmap,
                                                    const int4* __restrict__ gt,
                                                    float* __restrict__ ws) {
    __shared__ int4   gbuf[WAVES][4][WPR];   // 16 KB: gt rows, ring of 4
    __shared__ float4 cbuf[WAVES][4][WPR];   // 16 KB: cmap rows, ring of 4
    __shared__ float  sm[5][WAVES];

    const int tid   = threadIdx.x;
    const int lane  = tid & 63;
    const int wave  = tid >> 6;
    const int slice = blockIdx.x >> 4;        // / CPB
    const int chunk = blockIdx.x & (CPB - 1);
    const int R0    = chunk * RPB + wave * RPW;   // multiple of 16

    const float4* cm = cmap + slice * (Hn * WPR);
    const int4*   gs = gt   + slice * (Hn * WPR);

    // ---- prologue: VGPR loads for gt rows R0-1, R0 (window seed) ----
    const int rm = max(R0 - 1, 0);
    unsigned uA = pack4(gs[rm * WPR + lane]);
    unsigned uB = pack4(gs[rm * WPR + 64 + lane]);
    if (R0 == 0) { uA = 0u; uB = 0u; }
    unsigned cA = pack4(gs[R0 * WPR + lane]);
    unsigned cB = pack4(gs[R0 * WPR + 64 + lane]);

    // ---- prologue: 3 lookahead DMA batches (12 outstanding at loop entry) ----
    // R0 <= 496 so R0+3 <= 499 < Hn: no clamp needed here.
#pragma unroll
    for (int p = 1; p <= 3; ++p) {
        const int4*   gsrc = gs + (R0 + p) * WPR;
        const float4* csrc = cm + (R0 + p - 1) * WPR;
        gload_lds16(gsrc + lane,      &gbuf[wave][(R0 + p) & 3][lane]);
        gload_lds16(gsrc + 64 + lane, &gbuf[wave][(R0 + p) & 3][64 + lane]);
        gload_lds16(csrc + lane,      &cbuf[wave][(R0 + p - 1) & 3][lane]);
        gload_lds16(csrc + 64 + lane, &cbuf[wave][(R0 + p - 1) & 3][64 + lane]);
    }

    float cesum = 0.f, cxy = 0.f, ed = 0.f, inter = 0.f, jsum = 0.f;
    int icnt = 0;

#pragma unroll 4                              // r & 3 becomes compile-time
    for (int r = R0; r < R0 + RPW; ++r) {
        // ---- issue this iteration's DMA batch (always 4: count stays fixed) ----
        {
            const int gr = min(r + 4, Hn - 1);    // clamped rows land in dead slots
            const int cr = min(r + 3, Hn - 1);
            const int4*   gsrc = gs + gr * WPR;
            const float4* csrc = cm + cr * WPR;
            gload_lds16(gsrc + lane,      &gbuf[wave][(r + 4) & 3][lane]);
            gload_lds16(gsrc + 64 + lane, &gbuf[wave][(r + 4) & 3][64 + lane]);
            gload_lds16(csrc + lane,      &cbuf[wave][(r + 3) & 3][lane]);
            gload_lds16(csrc + 64 + lane, &cbuf[wave][(r + 3) & 3][64 + lane]);
        }
        // 16 outstanding -> drain to 12: completes [gt(r+1), cmap(r)] batch.
        asm volatile("s_waitcnt vmcnt(12)" ::: "memory");
        __builtin_amdgcn_sched_barrier(0);

        // ---- ds_read staged rows ----
        const int4 gA4 = gbuf[wave][(r + 1) & 3][lane];
        const int4 gB4 = gbuf[wave][(r + 1) & 3][64 + lane];
        unsigned dA = pack4(gA4), dB = pack4(gB4);
        if (r + 1 >= Hn) { dA = 0u; dB = 0u; }
        const float4 x0 = cbuf[wave][r & 3][lane];        // elems 4l .. 4l+3
        const float4 x1 = cbuf[wave][r & 3][64 + lane];   // elems 256+4l ..

        // ---- horizontal neighbors (contiguous mapping: 4 shfls + 2 bcasts) ----
        const unsigned firstB = __shfl(cB, 0);    // word 64 (elem 256)
        const unsigned lastA  = __shfl(cA, 63);   // word 63 (elem 252..255)
        unsigned pwA = __shfl_up(cA, 1);   if (lane == 0)  pwA = 0u;
        unsigned nxA = __shfl_down(cA, 1); if (lane == 63) nxA = firstB;
        unsigned pwB = __shfl_up(cB, 1);   if (lane == 0)  pwB = lastA;
        unsigned nxB = __shfl_down(cB, 1); if (lane == 63) nxB = 0u;

        const unsigned luA = (cA << 8) | (pwA >> 24);
        const unsigned ruA = (cA >> 8) | (nxA << 24);
        const unsigned luB = (cB << 8) | (pwB >> 24);
        const unsigned ruB = (cB >> 8) | (nxB << 24);

        // bytes are 0/1: dilation = OR, erosion = AND over the cross
        const unsigned ewA = (cA | uA | dA | luA | ruA) & ~(cA & uA & dA & luA & ruA);
        const unsigned ewB = (cB | uB | dB | luB | ruB) & ~(cB & uB & dB & luB & ruB);
        icnt += __popc(cA) + __popc(cB);

        const float xs[8] = {x0.x, x0.y, x0.z, x0.w, x1.x, x1.y, x1.z, x1.w};
#pragma unroll
        for (int e = 0; e < 8; ++e) {
            const unsigned cw = (e < 4) ? cA : cB;
            const unsigned ew = (e < 4) ? ewA : ewB;
            const int sh = 8 * (e & 3);
            const float xv = xs[e];
            const float t  = __expf(-fabsf(xv));            // exp(-|x|)
            const float u  = 1.f + t;
            const float sp = fmaxf(xv, 0.f) + __logf(u);    // softplus = logaddexp(0,x)
            const float rc = __builtin_amdgcn_rcpf(u);
            const float pred = (xv >= 0.f) ? rc : t * rc;   // sigmoid(x)
            const float yf = (float)((cw >> sh) & 1u);
            const float eb = (float)((ew >> sh) & 1u);

            cesum += sp;
            cxy   = fmaf(yf, xv, cxy);                      // ce = cesum - cxy
            inter = fmaf(yf, pred, inter);
            jsum += pred;
            ed    = fmaf(eb, fminf(sp, 100.f), ed);         // edge loss term
        }

        // roll vertical window
        uA = cA; uB = cB; cA = dA; cB = dB;
    }

    // ---- block reduction, one write per partial, no atomics ----
    const float v0 = wave_reduce(cesum - cxy);
    const float v1 = wave_reduce(ed);
    const float v2 = wave_reduce(inter);
    const float v3 = wave_reduce((float)icnt);
    const float v4 = wave_reduce(jsum);
    if (lane == 0) {
        sm[0][wave] = v0; sm[1][wave] = v1; sm[2][wave] = v2;
        sm[3][wave] = v3; sm[4][wave] = v4;
    }
    __syncthreads();
    if (tid < 5)
        ws[tid * NBLK + blockIdx.x] = sm[tid][0] + sm[tid][1];
}

__global__ void seg_finish(const float* __restrict__ ws, float* __restrict__ out) {
    const int t = threadIdx.x;                // 64 threads, one per (b,c) slice
    float ce = 0.f, ed = 0.f, inter = 0.f, is = 0.f, js = 0.f;
#pragma unroll 4
    for (int i = 0; i < CPB; ++i) {
        const int b = t * CPB + i;
        ce    += ws[0 * NBLK + b];
        ed    += ws[1 * NBLK + b];
        inter += ws[2 * NBLK + b];
        is    += ws[3 * NBLK + b];
        js    += ws[4 * NBLK + b];
    }
    const float score = (2.f * inter + SMOOTHF) / (is + js + SMOOTHF);
    float dice = (1.f - score) * (1.f / (float)Bn);   // mean over batch
    dice = wave_reduce(dice);                         // sum over classes (64 slices)
    ce = wave_reduce(ce);
    ed = wave_reduce(ed);
    if (t == 0)
        out[0] = ce * (1.f / NTOT) + ed * (1.f / NTOT) + dice;
}

extern "C" void kernel_launch(void* const* d_in, const int* in_sizes, int n_in,
                              void* d_out, int out_size, void* d_ws, size_t ws_size,
                              hipStream_t stream) {
    const float4* cmap = (const float4*)d_in[0];
    const int4*   gt   = (const int4*)d_in[1];
    float* ws = (float*)d_ws;                 // 5 * 1024 floats, fully rewritten
    seg_main<<<NBLK, BDIM, 0, stream>>>(cmap, gt, ws);
    seg_finish<<<1, 64, 0, stream>>>(ws, (float*)d_out);
}

// Round 7
// 146.118 us; speedup vs baseline: 1.0328x; 1.0328x over previous
//
#include <hip/hip_runtime.h>

#define BDIM 256
constexpr int Bn = 16, Cn = 4, Hn = 512, Wn = 512;
constexpr int SL   = Bn * Cn;          // 64 slices
constexpr int WPR  = Wn / 4;           // 128 int4/float4 words per row
constexpr int RPW  = 4;                // rows per wave
constexpr int RPB  = 16;               // rows per block (4 waves x 4 rows)
constexpr int CPB  = Hn / RPB;         // 32 chunks per slice
constexpr int NBLK = SL * CPB;         // 2048 blocks
constexpr float NTOT = 16777216.0f;    // B*C*H*W
constexpr float SMOOTHF = 0.0001f;

__device__ __forceinline__ float wave_reduce(float v) {
#pragma unroll
    for (int off = 32; off > 0; off >>= 1) v += __shfl_down(v, off);
    return v;
}

// Non-temporal 16B loads: set the `nt` bit -> bypass cache allocation.
// Round 1-6 evidence: HBM fetch rate pinned at 1.6-1.7 TB/s across SIX
// structures (occupancy 17-73%, MLP 1-16, VGPR vs LDS-DMA), with ~50% of
// demand served by L3 every iteration. Theory under test: the TCC path
// serializes on the mixed L3-hit/HBM-miss stream; forcing a pure HBM
// stream (no L3 allocation => no hits next iteration) unpins it.
typedef int   vi4 __attribute__((ext_vector_type(4)));
typedef float vf4 __attribute__((ext_vector_type(4)));

__device__ __forceinline__ int4 ldnt_i4(const int4* p) {
    vi4 v = __builtin_nontemporal_load((const vi4*)p);
    return make_int4(v.x, v.y, v.z, v.w);
}
__device__ __forceinline__ float4 ldnt_f4(const float4* p) {
    vf4 v = __builtin_nontemporal_load((const vf4*)p);
    return make_float4(v.x, v.y, v.z, v.w);
}

__device__ __forceinline__ unsigned pack4(int4 c) {
    return (unsigned)c.x | ((unsigned)c.y << 8) |
           ((unsigned)c.z << 16) | ((unsigned)c.w << 24);
}

// Deep-prologue streaming design (round-5 structure, best measured 44.6us)
// with ALL gt/cmap loads non-temporal. Single-variable experiment; see
// ldnt_* comment. Everything else identical to round 5.
// NO device-scope fences (round 2: per-block agent-scope fence = L2 flush,
// WRITE_SIZE 214 MB, 5x regression).
__global__ __launch_bounds__(BDIM, 4) void seg_main(const float4* __restrict__ cmap,
                                                    const int4* __restrict__ gt,
                                                    float* __restrict__ ws) {
    __shared__ float sm[5][4];

    const int tid   = threadIdx.x;
    const int lane  = tid & 63;
    const int wave  = tid >> 6;
    const int slice = blockIdx.x >> 5;        // / CPB
    const int chunk = blockIdx.x & (CPB - 1);
    const int R0    = chunk * RPB + wave * RPW;

    const float4* cm = cmap + slice * (Hn * WPR);
    const int4*   gs = gt   + slice * (Hn * WPR);
    const int wi = 2 * lane;                  // this lane: words wi, wi+1 (elems 8l..8l+7)

    // ---- prologue: issue all 20 loads back-to-back ----
    // gt rows staged: g[2j],g[2j+1] <-> gt row R0-1+j, j = 0..5
    int4 g[12];
    float4 xf[8];
    {
        const int rm = max(R0 - 1, 0);
        g[0]  = ldnt_i4(gs + rm * WPR + wi);
        g[1]  = ldnt_i4(gs + rm * WPR + wi + 1);
        g[2]  = ldnt_i4(gs + R0 * WPR + wi);
        g[3]  = ldnt_i4(gs + R0 * WPR + wi + 1);
        g[4]  = ldnt_i4(gs + (R0 + 1) * WPR + wi);      // R0+1 <= 509, valid
        g[5]  = ldnt_i4(gs + (R0 + 1) * WPR + wi + 1);
        xf[0] = ldnt_f4(cm + R0 * WPR + wi);
        xf[1] = ldnt_f4(cm + R0 * WPR + wi + 1);
        g[6]  = ldnt_i4(gs + (R0 + 2) * WPR + wi);      // <= 510
        g[7]  = ldnt_i4(gs + (R0 + 2) * WPR + wi + 1);
        xf[2] = ldnt_f4(cm + (R0 + 1) * WPR + wi);
        xf[3] = ldnt_f4(cm + (R0 + 1) * WPR + wi + 1);
        g[8]  = ldnt_i4(gs + (R0 + 3) * WPR + wi);      // <= 511
        g[9]  = ldnt_i4(gs + (R0 + 3) * WPR + wi + 1);
        xf[4] = ldnt_f4(cm + (R0 + 2) * WPR + wi);
        xf[5] = ldnt_f4(cm + (R0 + 2) * WPR + wi + 1);
        const int rl = min(R0 + 4, Hn - 1);
        g[10] = ldnt_i4(gs + rl * WPR + wi);
        g[11] = ldnt_i4(gs + rl * WPR + wi + 1);
        xf[6] = ldnt_f4(cm + (R0 + 3) * WPR + wi);
        xf[7] = ldnt_f4(cm + (R0 + 3) * WPR + wi + 1);
    }
    // Fence: loads cannot sink past a memory-clobber asm; compute cannot be
    // scheduled above sched_barrier(0). Forces all 20 loads in flight here.
    asm volatile("" ::: "memory");
    __builtin_amdgcn_sched_barrier(0);

    // pack first three gt rows (up / center / down for output row R0)
    unsigned u0 = pack4(g[0]), u1 = pack4(g[1]);
    if (R0 == 0) { u0 = 0u; u1 = 0u; }
    unsigned c0 = pack4(g[2]), c1 = pack4(g[3]);
    unsigned d0 = pack4(g[4]), d1 = pack4(g[5]);

    float cesum = 0.f, cxy = 0.f, ed = 0.f, inter = 0.f, jsum = 0.f;
    int icnt = 0;

#pragma unroll
    for (int k = 0; k < RPW; ++k) {
        // horizontal neighbors: intra-wave shfl; lane edges are the zero pad
        unsigned pw = __shfl_up(c1, 1);   if (lane == 0)  pw = 0u;
        unsigned nw = __shfl_down(c0, 1); if (lane == 63) nw = 0u;

        const unsigned l0 = (c0 << 8) | (pw >> 24);
        const unsigned r0 = (c0 >> 8) | ((c1 & 0xffu) << 24);
        const unsigned l1 = (c1 << 8) | (c0 >> 24);
        const unsigned r1 = (c1 >> 8) | (nw << 24);

        // bytes are 0/1: dilation = bitwise OR, erosion = bitwise AND
        const unsigned ew0 = (c0 | u0 | d0 | l0 | r0) & ~(c0 & u0 & d0 & l0 & r0);
        const unsigned ew1 = (c1 | u1 | d1 | l1 | r1) & ~(c1 & u1 & d1 & l1 & r1);
        icnt += __popc(c0) + __popc(c1);

        const float4 x0 = xf[2 * k];
        const float4 x1 = xf[2 * k + 1];
        const float xs[8] = {x0.x, x0.y, x0.z, x0.w, x1.x, x1.y, x1.z, x1.w};
#pragma unroll
        for (int e = 0; e < 8; ++e) {
            const unsigned cw = (e < 4) ? c0 : c1;
            const unsigned ew = (e < 4) ? ew0 : ew1;
            const int sh = 8 * (e & 3);
            const float xv = xs[e];
            const float t  = __expf(-fabsf(xv));            // exp(-|x|)
            const float u  = 1.f + t;
            const float sp = fmaxf(xv, 0.f) + __logf(u);    // softplus = logaddexp(0,x)
            const float rc = __builtin_amdgcn_rcpf(u);
            const float pred = (xv >= 0.f) ? rc : t * rc;   // sigmoid(x)
            const float yf = (float)((cw >> sh) & 1u);
            const float eb = (float)((ew >> sh) & 1u);

            cesum += sp;
            cxy   = fmaf(yf, xv, cxy);                      // ce = cesum - cxy
            inter = fmaf(yf, pred, inter);
            jsum += pred;
            ed    = fmaf(eb, fminf(sp, 100.f), ed);         // edge loss term
        }

        // roll vertical window; pack next down-row (gt row R0+k+2)
        if (k < RPW - 1) {
            u0 = c0; u1 = c1; c0 = d0; c1 = d1;
            unsigned t0 = pack4(g[2 * k + 6]), t1 = pack4(g[2 * k + 7]);
            if (R0 + k + 2 >= Hn) { t0 = 0u; t1 = 0u; }
            d0 = t0; d1 = t1;
        }
    }

    // ---- block reduction, one write per partial, no atomics ----
    const float v0 = wave_reduce(cesum - cxy);
    const float v1 = wave_reduce(ed);
    const float v2 = wave_reduce(inter);
    const float v3 = wave_reduce((float)icnt);
    const float v4 = wave_reduce(jsum);
    if (lane == 0) {
        sm[0][wave] = v0; sm[1][wave] = v1; sm[2][wave] = v2;
        sm[3][wave] = v3; sm[4][wave] = v4;
    }
    __syncthreads();
    if (tid < 5)
        ws[tid * NBLK + blockIdx.x] = sm[tid][0] + sm[tid][1] + sm[tid][2] + sm[tid][3];
}

__global__ void seg_finish(const float* __restrict__ ws, float* __restrict__ out) {
    const int t = threadIdx.x;                // 64 threads, one per (b,c) slice
    float ce = 0.f, ed = 0.f, inter = 0.f, is = 0.f, js = 0.f;
#pragma unroll 8
    for (int i = 0; i < CPB; ++i) {
        const int b = t * CPB + i;
        ce    += ws[0 * NBLK + b];
        ed    += ws[1 * NBLK + b];
        inter += ws[2 * NBLK + b];
        is    += ws[3 * NBLK + b];
        js    += ws[4 * NBLK + b];
    }
    const float score = (2.f * inter + SMOOTHF) / (is + js + SMOOTHF);
    float dice = (1.f - score) * (1.f / (float)Bn);   // mean over batch
    dice = wave_reduce(dice);                         // sum over classes (64 slices)
    ce = wave_reduce(ce);
    ed = wave_reduce(ed);
    if (t == 0)
        out[0] = ce * (1.f / NTOT) + ed * (1.f / NTOT) + dice;
}

extern "C" void kernel_launch(void* const* d_in, const int* in_sizes, int n_in,
                              void* d_out, int out_size, void* d_ws, size_t ws_size,
                              hipStream_t stream) {
    const float4* cmap = (const float4*)d_in[0];
    const int4*   gt   = (const int4*)d_in[1];
    float* ws = (float*)d_ws;                 // 5 * 2048 floats, fully rewritten
    seg_main<<<NBLK, BDIM, 0, stream>>>(cmap, gt, ws);
    seg_finish<<<1, 64, 0, stream>>>(ws, (float*)d_out);
}

// Round 8
// 134.417 us; speedup vs baseline: 1.1227x; 1.0871x over previous
//
#include <hip/hip_runtime.h>

#define BDIM 256
constexpr int Bn = 16, Cn = 4, Hn = 512, Wn = 512;
constexpr int SL   = Bn * Cn;          // 64 slices
constexpr int WPR  = Wn / 4;           // 128 int4/float4 words per row
constexpr int RPW  = 4;                // rows per wave
constexpr int RPB  = 16;               // rows per block (4 waves x 4 rows)
constexpr int CPB  = Hn / RPB;         // 32 chunks per slice
constexpr int NBLK = SL * CPB;         // 2048 blocks
constexpr float NTOT = 16777216.0f;    // B*C*H*W
constexpr float SMOOTHF = 0.0001f;

__device__ __forceinline__ float wave_reduce(float v) {
#pragma unroll
    for (int off = 32; off > 0; off >>= 1) v += __shfl_down(v, off);
    return v;
}

// Round-7 result: ALL-nt loads took seg_main from 44.6us to <40us (fell out
// of top-5; harness fills at 40us now dominate) -- the 1.6-1.7 TB/s fetch
// pin across rounds 1-6 was the mixed L3-hit/HBM-miss stream, and the chip
// sustains 6.7 TB/s on pure streams (fillBuffer evidence).
// Round-8 single-variable split: cmap (64 MB, zero reuse, 40% of demand)
// stays nt (pure HBM stream, no L3 pollution); gt (64 MB unique, 1.5x read
// due to halo) goes back to CACHED so halo re-reads hit L3 instead of HBM.
// HBM demand: 160 MB (full-nt) -> ~128 MB. If any cached fraction re-pins
// the TCC path, this regresses toward 44us -> revert to full-nt + roofline.
typedef float vf4 __attribute__((ext_vector_type(4)));

__device__ __forceinline__ float4 ldnt_f4(const float4* p) {
    vf4 v = __builtin_nontemporal_load((const vf4*)p);
    return make_float4(v.x, v.y, v.z, v.w);
}

__device__ __forceinline__ unsigned pack4(int4 c) {
    return (unsigned)c.x | ((unsigned)c.y << 8) |
           ((unsigned)c.z << 16) | ((unsigned)c.w << 24);
}

// Deep-prologue streaming design (round-5/7 structure). 20 loads issued
// back-to-back, compiler fence pins issue order, counted vmcnt waits.
// NO device-scope fences (round 2: per-block agent-scope fence = L2 flush,
// WRITE_SIZE 214 MB, 5x regression).
__global__ __launch_bounds__(BDIM, 4) void seg_main(const float4* __restrict__ cmap,
                                                    const int4* __restrict__ gt,
                                                    float* __restrict__ ws) {
    __shared__ float sm[5][4];

    const int tid   = threadIdx.x;
    const int lane  = tid & 63;
    const int wave  = tid >> 6;
    const int slice = blockIdx.x >> 5;        // / CPB
    const int chunk = blockIdx.x & (CPB - 1);
    const int R0    = chunk * RPB + wave * RPW;

    const float4* cm = cmap + slice * (Hn * WPR);
    const int4*   gs = gt   + slice * (Hn * WPR);
    const int wi = 2 * lane;                  // this lane: words wi, wi+1 (elems 8l..8l+7)

    // ---- prologue: issue all 20 loads back-to-back ----
    // gt rows staged: g[2j],g[2j+1] <-> gt row R0-1+j, j = 0..5   (CACHED)
    // cmap rows xf[2k],xf[2k+1] <-> row R0+k, k = 0..3            (NT)
    int4 g[12];
    float4 xf[8];
    {
        const int rm = max(R0 - 1, 0);
        g[0]  = gs[rm * WPR + wi];
        g[1]  = gs[rm * WPR + wi + 1];
        g[2]  = gs[R0 * WPR + wi];
        g[3]  = gs[R0 * WPR + wi + 1];
        g[4]  = gs[(R0 + 1) * WPR + wi];      // R0+1 <= 509, valid
        g[5]  = gs[(R0 + 1) * WPR + wi + 1];
        xf[0] = ldnt_f4(cm + R0 * WPR + wi);
        xf[1] = ldnt_f4(cm + R0 * WPR + wi + 1);
        g[6]  = gs[(R0 + 2) * WPR + wi];      // <= 510
        g[7]  = gs[(R0 + 2) * WPR + wi + 1];
        xf[2] = ldnt_f4(cm + (R0 + 1) * WPR + wi);
        xf[3] = ldnt_f4(cm + (R0 + 1) * WPR + wi + 1);
        g[8]  = gs[(R0 + 3) * WPR + wi];      // <= 511
        g[9]  = gs[(R0 + 3) * WPR + wi + 1];
        xf[4] = ldnt_f4(cm + (R0 + 2) * WPR + wi);
        xf[5] = ldnt_f4(cm + (R0 + 2) * WPR + wi + 1);
        const int rl = min(R0 + 4, Hn - 1);
        g[10] = gs[rl * WPR + wi];
        g[11] = gs[rl * WPR + wi + 1];
        xf[6] = ldnt_f4(cm + (R0 + 3) * WPR + wi);
        xf[7] = ldnt_f4(cm + (R0 + 3) * WPR + wi + 1);
    }
    // Fence: loads cannot sink past a memory-clobber asm; compute cannot be
    // scheduled above sched_barrier(0). Forces the load burst to issue here.
    asm volatile("" ::: "memory");
    __builtin_amdgcn_sched_barrier(0);

    // pack first three gt rows (up / center / down for output row R0)
    unsigned u0 = pack4(g[0]), u1 = pack4(g[1]);
    if (R0 == 0) { u0 = 0u; u1 = 0u; }
    unsigned c0 = pack4(g[2]), c1 = pack4(g[3]);
    unsigned d0 = pack4(g[4]), d1 = pack4(g[5]);

    float cesum = 0.f, cxy = 0.f, ed = 0.f, inter = 0.f, jsum = 0.f;
    int icnt = 0;

#pragma unroll
    for (int k = 0; k < RPW; ++k) {
        // horizontal neighbors: intra-wave shfl; lane edges are the zero pad
        unsigned pw = __shfl_up(c1, 1);   if (lane == 0)  pw = 0u;
        unsigned nw = __shfl_down(c0, 1); if (lane == 63) nw = 0u;

        const unsigned l0 = (c0 << 8) | (pw >> 24);
        const unsigned r0 = (c0 >> 8) | ((c1 & 0xffu) << 24);
        const unsigned l1 = (c1 << 8) | (c0 >> 24);
        const unsigned r1 = (c1 >> 8) | (nw << 24);

        // bytes are 0/1: dilation = bitwise OR, erosion = bitwise AND
        const unsigned ew0 = (c0 | u0 | d0 | l0 | r0) & ~(c0 & u0 & d0 & l0 & r0);
        const unsigned ew1 = (c1 | u1 | d1 | l1 | r1) & ~(c1 & u1 & d1 & l1 & r1);
        icnt += __popc(c0) + __popc(c1);

        const float4 x0 = xf[2 * k];
        const float4 x1 = xf[2 * k + 1];
        const float xs[8] = {x0.x, x0.y, x0.z, x0.w, x1.x, x1.y, x1.z, x1.w};
#pragma unroll
        for (int e = 0; e < 8; ++e) {
            const unsigned cw = (e < 4) ? c0 : c1;
            const unsigned ew = (e < 4) ? ew0 : ew1;
            const int sh = 8 * (e & 3);
            const float xv = xs[e];
            const float t  = __expf(-fabsf(xv));            // exp(-|x|)
            const float u  = 1.f + t;
            const float sp = fmaxf(xv, 0.f) + __logf(u);    // softplus = logaddexp(0,x)
            const float rc = __builtin_amdgcn_rcpf(u);
            const float pred = (xv >= 0.f) ? rc : t * rc;   // sigmoid(x)
            const float yf = (float)((cw >> sh) & 1u);
            const float eb = (float)((ew >> sh) & 1u);

            cesum += sp;
            cxy   = fmaf(yf, xv, cxy);                      // ce = cesum - cxy
            inter = fmaf(yf, pred, inter);
            jsum += pred;
            ed    = fmaf(eb, fminf(sp, 100.f), ed);         // edge loss term
        }

        // roll vertical window; pack next down-row (gt row R0+k+2)
        if (k < RPW - 1) {
            u0 = c0; u1 = c1; c0 = d0; c1 = d1;
            unsigned t0 = pack4(g[2 * k + 6]), t1 = pack4(g[2 * k + 7]);
            if (R0 + k + 2 >= Hn) { t0 = 0u; t1 = 0u; }
            d0 = t0; d1 = t1;
        }
    }

    // ---- block reduction, one write per partial, no atomics ----
    const float v0 = wave_reduce(cesum - cxy);
    const float v1 = wave_reduce(ed);
    const float v2 = wave_reduce(inter);
    const float v3 = wave_reduce((float)icnt);
    const float v4 = wave_reduce(jsum);
    if (lane == 0) {
        sm[0][wave] = v0; sm[1][wave] = v1; sm[2][wave] = v2;
        sm[3][wave] = v3; sm[4][wave] = v4;
    }
    __syncthreads();
    if (tid < 5)
        ws[tid * NBLK + blockIdx.x] = sm[tid][0] + sm[tid][1] + sm[tid][2] + sm[tid][3];
}

__global__ void seg_finish(const float* __restrict__ ws, float* __restrict__ out) {
    const int t = threadIdx.x;                // 64 threads, one per (b,c) slice
    float ce = 0.f, ed = 0.f, inter = 0.f, is = 0.f, js = 0.f;
#pragma unroll 8
    for (int i = 0; i < CPB; ++i) {
        const int b = t * CPB + i;
        ce    += ws[0 * NBLK + b];
        ed    += ws[1 * NBLK + b];
        inter += ws[2 * NBLK + b];
        is    += ws[3 * NBLK + b];
        js    += ws[4 * NBLK + b];
    }
    const float score = (2.f * inter + SMOOTHF) / (is + js + SMOOTHF);
    float dice = (1.f - score) * (1.f / (float)Bn);   // mean over batch
    dice = wave_reduce(dice);                         // sum over classes (64 slices)
    ce = wave_reduce(ce);
    ed = wave_reduce(ed);
    if (t == 0)
        out[0] = ce * (1.f / NTOT) + ed * (1.f / NTOT) + dice;
}

extern "C" void kernel_launch(void* const* d_in, const int* in_sizes, int n_in,
                              void* d_out, int out_size, void* d_ws, size_t ws_size,
                              hipStream_t stream) {
    const float4* cmap = (const float4*)d_in[0];
    const int4*   gt   = (const int4*)d_in[1];
    float* ws = (float*)d_ws;                 // 5 * 2048 floats, fully rewritten
    seg_main<<<NBLK, BDIM, 0, stream>>>(cmap, gt, ws);
    seg_finish<<<1, 64, 0, stream>>>(ws, (float*)d_out);
}